// Round 1
// 104.549 us; speedup vs baseline: 1.2103x; 1.2103x over previous
//
#include <hip/hip_runtime.h>
#include <hip/hip_bf16.h>

#define NB 32
#define NSEQ 3136
#define NDIM 64
#define NH 8
#define NAG 49

static constexpr float kScale = 0.35355339059327378f; // 8^-0.5

typedef unsigned short us;
typedef __attribute__((ext_vector_type(8))) __bf16 bf16x8;
typedef __attribute__((ext_vector_type(4))) __bf16 bf16x4;
typedef __attribute__((ext_vector_type(2))) _Float16 f16x2;
typedef __attribute__((ext_vector_type(4))) _Float16 f16x4;
typedef __attribute__((ext_vector_type(4))) float f32x4;
typedef __attribute__((ext_vector_type(2))) float f32x2;

__device__ __forceinline__ f32x2 up2(unsigned int u) { // {lo,hi} bf16 pair -> f32x2
  return (f32x2){__uint_as_float(u << 16), __uint_as_float(u & 0xffff0000u)};
}

// ---------------------------------------------------------------------------
// Kernel P: convert Wq,Wk,Wv (64x64) and Wo (128x128) to bf16.
// ---------------------------------------------------------------------------
__global__ __launch_bounds__(256) void prep_kernel(
    const float* __restrict__ Wq, const float* __restrict__ Wk,
    const float* __restrict__ Wv, const float* __restrict__ Wo,
    __bf16* __restrict__ wq, __bf16* __restrict__ wk, __bf16* __restrict__ wv,
    __bf16* __restrict__ wo) {
  int i = blockIdx.x * 256 + threadIdx.x; // 64 blocks -> 16384
  wo[i] = (__bf16)Wo[i];
  if (i < 4096) { wq[i] = (__bf16)Wq[i]; wk[i] = (__bf16)Wk[i]; wv[i] = (__bf16)Wv[i]; }
}

// ---------------------------------------------------------------------------
// Kernel A: kv^T GEMM via swapped MFMA operands (C = W @ x2^T) so each lane
// holds 4 consecutive FEATURES of one token -> direct f16 global stores, no
// LDS transpose. agent = kScale * (colsum(x1)/64) @ Wq^T in f32 (mean-first).
// kvh[b,h,j][0..7]=k f16, [8..15]=v f16. grid (49,32), block 256 (4 waves).
// ---------------------------------------------------------------------------
__global__ __launch_bounds__(256, 4) void qkv_agent_kernel(
    const float* __restrict__ x1, const float* __restrict__ x2,
    const float* __restrict__ Wq, const __bf16* __restrict__ wk,
    const __bf16* __restrict__ wv, us* __restrict__ kvh,
    float* __restrict__ agent) {
  __shared__ __align__(16) __bf16 xb[64][72];
  __shared__ __align__(16) float red[4][64];
  __shared__ __align__(16) float marr[64];
  const int a = blockIdx.x, b = blockIdx.y, t = threadIdx.x;
  const int i64 = t & 63, cb = t >> 6;
  const int w = cb, lr = (t >> 4) & 3, lc = t & 15;

  // prefetch A-frags (W rows; independent of LDS, overlaps staging)
  bf16x8 ak0 = *(const bf16x8*)(wk + (size_t)(w * 16 + lc) * NDIM + lr * 8);
  bf16x8 ak1 = *(const bf16x8*)(wk + (size_t)(w * 16 + lc) * NDIM + 32 + lr * 8);
  bf16x8 av0 = *(const bf16x8*)(wv + (size_t)(w * 16 + lc) * NDIM + lr * 8);
  bf16x8 av1 = *(const bf16x8*)(wv + (size_t)(w * 16 + lc) * NDIM + 32 + lr * 8);

  // stage x2 tile as bf16 (thread: one row, 16 cols)
  {
    const float4* s2 = (const float4*)(x2 + ((size_t)(b * NSEQ) + a * 64 + i64) * NDIM + cb * 16);
    float4 v0 = s2[0], v1 = s2[1], v2 = s2[2], v3 = s2[3];
    bf16x8 p0, p1;
    p0[0]=(__bf16)v0.x; p0[1]=(__bf16)v0.y; p0[2]=(__bf16)v0.z; p0[3]=(__bf16)v0.w;
    p0[4]=(__bf16)v1.x; p0[5]=(__bf16)v1.y; p0[6]=(__bf16)v1.z; p0[7]=(__bf16)v1.w;
    p1[0]=(__bf16)v2.x; p1[1]=(__bf16)v2.y; p1[2]=(__bf16)v2.z; p1[3]=(__bf16)v2.w;
    p1[4]=(__bf16)v3.x; p1[5]=(__bf16)v3.y; p1[6]=(__bf16)v3.z; p1[7]=(__bf16)v3.w;
    *(bf16x8*)&xb[i64][cb * 16] = p0; *(bf16x8*)&xb[i64][cb * 16 + 8] = p1;
  }
  // x1 column partial sums (wave reads are fully coalesced: 64 lanes = 64 cols)
  {
    const float* xc = x1 + ((size_t)(b * NSEQ) + a * 64 + cb * 16) * NDIM + i64;
    float cs = 0.f;
#pragma unroll
    for (int i = 0; i < 16; ++i) cs += xc[i * NDIM];
    red[cb][i64] = cs;
  }
  __syncthreads();

  // kv^T GEMM: wave w covers k-feats [w*16,w*16+16) and v-feats likewise.
  f32x4 acck[4], accv[4];
#pragma unroll
  for (int i = 0; i < 4; ++i) {
    acck[i] = (f32x4){0.f, 0.f, 0.f, 0.f};
    accv[i] = (f32x4){0.f, 0.f, 0.f, 0.f};
  }
#pragma unroll
  for (int nt = 0; nt < 4; ++nt) {
    bf16x8 x0 = *(const bf16x8*)&xb[nt * 16 + lc][lr * 8];
    bf16x8 x1f = *(const bf16x8*)&xb[nt * 16 + lc][32 + lr * 8];
    acck[nt] = __builtin_amdgcn_mfma_f32_16x16x32_bf16(ak0, x0, acck[nt], 0, 0, 0);
    acck[nt] = __builtin_amdgcn_mfma_f32_16x16x32_bf16(ak1, x1f, acck[nt], 0, 0, 0);
    accv[nt] = __builtin_amdgcn_mfma_f32_16x16x32_bf16(av0, x0, accv[nt], 0, 0, 0);
    accv[nt] = __builtin_amdgcn_mfma_f32_16x16x32_bf16(av1, x1f, accv[nt], 0, 0, 0);
  }
  // C layout: row = feat = lr*4+j (within wave's 16), col = tok = nt*16+lc.
  // feat f = w*16+lr*4+j -> head = f>>3 = 2w + (lr>>1), slot = (lr&1)*4 + j.
  const int head = 2 * w + (lr >> 1), sb = (lr & 1) * 4;
#pragma unroll
  for (int nt = 0; nt < 4; ++nt) {
    _Float16* dst = (_Float16*)kvh +
        (((size_t)(b * NH + head) * NSEQ) + a * 64 + nt * 16 + lc) * 16 + sb;
    f16x4 pk, pv;
    pk[0]=(_Float16)acck[nt][0]; pk[1]=(_Float16)acck[nt][1];
    pk[2]=(_Float16)acck[nt][2]; pk[3]=(_Float16)acck[nt][3];
    pv[0]=(_Float16)accv[nt][0]; pv[1]=(_Float16)accv[nt][1];
    pv[2]=(_Float16)accv[nt][2]; pv[3]=(_Float16)accv[nt][3];
    *(f16x4*)dst = pk;
    *(f16x4*)(dst + 8) = pv;
  }

  // agent via mean-first (linearity of pooling): f32 all the way.
  if (t < 64) marr[t] = red[0][t] + red[1][t] + red[2][t] + red[3][t];
  __syncthreads();
  if (t < 64) {
    const float4* wqr = (const float4*)(Wq + (size_t)t * NDIM);
    const float4* mm = (const float4*)marr;
    float s0 = 0.f;
#pragma unroll
    for (int i = 0; i < 16; ++i) {
      float4 wv4 = wqr[i], m4 = mm[i];
      s0 += wv4.x * m4.x + wv4.y * m4.y + wv4.z * m4.z + wv4.w * m4.w;
    }
    agent[(((size_t)b * NH + (t >> 3)) * NAG + a) * 8 + (t & 7)] = s0 * (kScale / 64.f);
  }
}

// ---------------------------------------------------------------------------
// Kernel B: stage-0 attention. ao[b,h,a] = [agent(8) | softmax_n(agent.k)@v (8)]
// grid (8, 32), block 1024 (16 waves). lane = agent; k/v (f16) streamed via
// wave-uniform 32B rows; v_dot2_f32_f16 + mix-friendly FMAs.
// ---------------------------------------------------------------------------
__global__ __launch_bounds__(1024, 2) void stage0_kernel(
    const us* __restrict__ kvh, const float* __restrict__ agent,
    float* __restrict__ ao) {
  __shared__ float red[16][NAG][9]; // 28224B
  const int h = blockIdx.x, b = blockIdx.y;
  const int t = threadIdx.x, lane = t & 63;
  const int w = __builtin_amdgcn_readfirstlane(t >> 6);
  const int a = lane < NAG ? lane : NAG - 1;

  float a0,a1,a2,a3,a4,a5,a6,a7;
  {
    const float4* ap = (const float4*)(agent + (((size_t)b * NH + h) * NAG + a) * 8);
    float4 g0 = ap[0], g1 = ap[1];
    a0=g0.x; a1=g0.y; a2=g0.z; a3=g0.w; a4=g1.x; a5=g1.y; a6=g1.z; a7=g1.w;
  }
  f16x2 ah0 = {(_Float16)a0, (_Float16)a1}, ah1 = {(_Float16)a2, (_Float16)a3};
  f16x2 ah2 = {(_Float16)a4, (_Float16)a5}, ah3 = {(_Float16)a6, (_Float16)a7};
  const us* kb = kvh + (((size_t)b * NH + h) * NSEQ + (size_t)w * (NSEQ / 16)) * 16;

  float s = 0.f;
  float o0=0,o1=0,o2=0,o3=0,o4=0,o5=0,o6=0,o7=0;
#pragma unroll 4
  for (int j = 0; j < NSEQ / 16; ++j) {
    const us* r = kb + (size_t)j * 16;
    uint4 ku = *(const uint4*)r;       // wave-uniform 16B (k, f16)
    uint4 vu = *(const uint4*)(r + 8); // wave-uniform 16B (v, f16)
#if __has_builtin(__builtin_amdgcn_fdot2)
    float lg = __builtin_amdgcn_fdot2(ah0, __builtin_bit_cast(f16x2, ku.x), 0.f, false);
    lg = __builtin_amdgcn_fdot2(ah1, __builtin_bit_cast(f16x2, ku.y), lg, false);
    lg = __builtin_amdgcn_fdot2(ah2, __builtin_bit_cast(f16x2, ku.z), lg, false);
    lg = __builtin_amdgcn_fdot2(ah3, __builtin_bit_cast(f16x2, ku.w), lg, false);
#else
    f16x2 k01 = __builtin_bit_cast(f16x2, ku.x), k23 = __builtin_bit_cast(f16x2, ku.y);
    f16x2 k45 = __builtin_bit_cast(f16x2, ku.z), k67 = __builtin_bit_cast(f16x2, ku.w);
    float lg = a0*(float)k01[0] + a1*(float)k01[1] + a2*(float)k23[0] + a3*(float)k23[1]
             + a4*(float)k45[0] + a5*(float)k45[1] + a6*(float)k67[0] + a7*(float)k67[1];
#endif
    float p = __expf(lg);
    s += p;
    f16x2 v01 = __builtin_bit_cast(f16x2, vu.x), v23 = __builtin_bit_cast(f16x2, vu.y);
    f16x2 v45 = __builtin_bit_cast(f16x2, vu.z), v67 = __builtin_bit_cast(f16x2, vu.w);
    o0 += p * (float)v01[0]; o1 += p * (float)v01[1];
    o2 += p * (float)v23[0]; o3 += p * (float)v23[1];
    o4 += p * (float)v45[0]; o5 += p * (float)v45[1];
    o6 += p * (float)v67[0]; o7 += p * (float)v67[1];
  }
  if (lane < NAG) {
    float* rr = red[t >> 6][lane];
    rr[0] = s; rr[1] = o0; rr[2] = o1; rr[3] = o2; rr[4] = o3;
    rr[5] = o4; rr[6] = o5; rr[7] = o6; rr[8] = o7;
  }
  __syncthreads();
  if (t < NAG) {
    float S = 0.f, A0=0, A1=0, A2=0, A3=0, A4=0, A5=0, A6=0, A7=0;
#pragma unroll
    for (int ww = 0; ww < 16; ++ww) {
      const float* r = red[ww][t];
      S += r[0]; A0 += r[1]; A1 += r[2]; A2 += r[3]; A3 += r[4];
      A4 += r[5]; A5 += r[6]; A6 += r[7]; A7 += r[8];
    }
    float inv = 1.f / S;
    const float* ap2 = agent + (((size_t)b * NH + h) * NAG + t) * 8;
    float* orow = ao + (((size_t)b * NH + h) * NAG + t) * 16;
    float4 g0 = *(const float4*)ap2, g1 = *(const float4*)(ap2 + 4);
    *(float4*)orow = g0; *(float4*)(orow + 4) = g1;
    *(float4*)(orow + 8)  = (float4){A0*inv, A1*inv, A2*inv, A3*inv};
    *(float4*)(orow + 12) = (float4){A4*inv, A5*inv, A6*inv, A7*inv};
  }
}

// ---------------------------------------------------------------------------
// Kernel C: stage-1 attention + output linear, fused.
// grid (49, 32), block 512 (8 waves). Only 3 barriers:
//   q^T GEMM (swapped: C lanes hold consecutive q feats -> b64 LDS writes),
//   packed f32x2 softmax loop (ao streamed wave-uniform, v_rcp),
//   out^T GEMM (swapped: C lanes hold 4 consecutive out feats of one token ->
//   direct coalescing-friendly dwordx4 global stores with in-register bias).
// ---------------------------------------------------------------------------
__global__ __launch_bounds__(512, 4) void stage1_out_kernel(
    const float* __restrict__ x1, const __bf16* __restrict__ wq,
    const float* __restrict__ ao, const __bf16* __restrict__ wo,
    const float* __restrict__ bo, float* __restrict__ out) {
  __shared__ __align__(16) __bf16 xa[64][72];
  __shared__ __align__(16) __bf16 qld[64][72];
  __shared__ __align__(16) __bf16 catL[64][72];
  const int tile = blockIdx.x, b = blockIdx.y;
  const int t = threadIdx.x, tokl = t & 63, h = t >> 6;
  const int w = h, lr = (t >> 4) & 3, lc = t & 15;
  const int mtile = w & 3, thalf = w >> 2;

  // prefetch weight A-frags + bias (global; overlap with staging + barriers)
  bf16x8 wqf0 = *(const bf16x8*)(wq + (size_t)(mtile * 16 + lc) * NDIM + lr * 8);
  bf16x8 wqf1 = *(const bf16x8*)(wq + (size_t)(mtile * 16 + lc) * NDIM + 32 + lr * 8);
  bf16x8 wof[4];
#pragma unroll
  for (int ks = 0; ks < 4; ++ks)
    wof[ks] = *(const bf16x8*)(wo + (size_t)(w * 16 + lc) * 128 + ks * 32 + lr * 8);
  f32x4 bv = *(const f32x4*)(bo + w * 16 + lr * 4);

  // stage x1 tile bf16 (thread: token tokl, cols h*8..h*8+7)
  {
    const float4* src = (const float4*)(x1 + ((size_t)b * NSEQ + tile * 64 + tokl) * NDIM + h * 8);
    float4 v0 = src[0], v1 = src[1];
    bf16x8 p;
    p[0]=(__bf16)v0.x; p[1]=(__bf16)v0.y; p[2]=(__bf16)v0.z; p[3]=(__bf16)v0.w;
    p[4]=(__bf16)v1.x; p[5]=(__bf16)v1.y; p[6]=(__bf16)v1.z; p[7]=(__bf16)v1.w;
    *(bf16x8*)&xa[tokl][h * 8] = p;
  }
  __syncthreads();

  // q^T = Wq @ x1^T (wave w: feat tile mtile, token half thalf) -> qld bf16
  {
    f32x4 aq[2];
    aq[0] = (f32x4){0.f,0.f,0.f,0.f}; aq[1] = (f32x4){0.f,0.f,0.f,0.f};
#pragma unroll
    for (int nt = 0; nt < 2; ++nt) {
      bf16x8 bx0 = *(const bf16x8*)&xa[thalf * 32 + nt * 16 + lc][lr * 8];
      bf16x8 bx1 = *(const bf16x8*)&xa[thalf * 32 + nt * 16 + lc][32 + lr * 8];
      aq[nt] = __builtin_amdgcn_mfma_f32_16x16x32_bf16(wqf0, bx0, aq[nt], 0, 0, 0);
      aq[nt] = __builtin_amdgcn_mfma_f32_16x16x32_bf16(wqf1, bx1, aq[nt], 0, 0, 0);
    }
#pragma unroll
    for (int nt = 0; nt < 2; ++nt) {
      bf16x4 pk;
      pk[0]=(__bf16)aq[nt][0]; pk[1]=(__bf16)aq[nt][1];
      pk[2]=(__bf16)aq[nt][2]; pk[3]=(__bf16)aq[nt][3];
      *(bf16x4*)&qld[thalf * 32 + nt * 16 + lc][mtile * 16 + lr * 4] = pk;
    }
  }
  __syncthreads();

  // stage-1 attention: thread = (tokl, h); ao streamed wave-uniform; pk math
  {
    uint4 qv = *(const uint4*)&qld[tokl][h * 8];
    f32x2 q01 = up2(qv.x), q23 = up2(qv.y), q45 = up2(qv.z), q67 = up2(qv.w);
    const int hh = __builtin_amdgcn_readfirstlane(h);
    const float* aob = ao + ((size_t)b * NH + hh) * NAG * 16;
    float s = 0.f;
    f32x2 o01 = {0.f,0.f}, o23 = {0.f,0.f}, o45 = {0.f,0.f}, o67 = {0.f,0.f};
#pragma unroll 7
    for (int a2 = 0; a2 < NAG; ++a2) {
      const f32x2* r = (const f32x2*)(aob + (size_t)a2 * 16);
      f32x2 d = q01 * r[0];
      d += q23 * r[1];
      d += q45 * r[2];
      d += q67 * r[3];
      float p = __expf(d[0] + d[1]);
      s += p;
      f32x2 pp = {p, p};
      o01 += pp * r[4]; o23 += pp * r[5]; o45 += pp * r[6]; o67 += pp * r[7];
    }
#if __has_builtin(__builtin_amdgcn_rcpf)
    float inv = __builtin_amdgcn_rcpf(s);
#else
    float inv = 1.f / s;
#endif
    bf16x8 pc;
    pc[0]=(__bf16)(o01[0]*inv); pc[1]=(__bf16)(o01[1]*inv);
    pc[2]=(__bf16)(o23[0]*inv); pc[3]=(__bf16)(o23[1]*inv);
    pc[4]=(__bf16)(o45[0]*inv); pc[5]=(__bf16)(o45[1]*inv);
    pc[6]=(__bf16)(o67[0]*inv); pc[7]=(__bf16)(o67[1]*inv);
    *(bf16x8*)&catL[tokl][h * 8] = pc;
  }
  __syncthreads();

  // out^T = Wo @ [catL|xa]^T; direct stores (lane: 4 consecutive feats of 1 tok)
  {
    f32x4 acc[4];
#pragma unroll
    for (int i = 0; i < 4; ++i) acc[i] = (f32x4){0.f,0.f,0.f,0.f};
#pragma unroll
    for (int ks = 0; ks < 4; ++ks) {
#pragma unroll
      for (int nt = 0; nt < 4; ++nt) {
        bf16x8 bx = (ks < 2) ? *(const bf16x8*)&catL[nt * 16 + lc][ks * 32 + lr * 8]
                             : *(const bf16x8*)&xa[nt * 16 + lc][(ks - 2) * 32 + lr * 8];
        acc[nt] = __builtin_amdgcn_mfma_f32_16x16x32_bf16(wof[ks], bx, acc[nt], 0, 0, 0);
      }
    }
#pragma unroll
    for (int nt = 0; nt < 4; ++nt) {
      f32x4 v = acc[nt] + bv;
      float* dst = out + ((size_t)b * NSEQ + tile * 64 + nt * 16 + lc) * 128 + w * 16 + lr * 4;
      *(f32x4*)dst = v;
    }
  }
}

extern "C" void kernel_launch(void* const* d_in, const int* in_sizes, int n_in,
                              void* d_out, int out_size, void* d_ws, size_t ws_size,
                              hipStream_t stream) {
  (void)in_sizes; (void)n_in; (void)out_size; (void)ws_size;
  const float* x1 = (const float*)d_in[0];
  const float* x2 = (const float*)d_in[1];
  const float* Wq = (const float*)d_in[2];
  const float* Wk = (const float*)d_in[3];
  const float* Wv = (const float*)d_in[4];
  const float* Wo = (const float*)d_in[5];
  const float* bo = (const float*)d_in[6];
  float* out = (float*)d_out;

  us* kvh = (us*)d_ws;                                        // 32*8*3136*16 f16 = 25.7MB
  float* agent = (float*)(kvh + (size_t)NB * NH * NSEQ * 16); // 100352 f32
  float* ao = agent + (size_t)NB * NH * NAG * 8;              // 200704 f32
  __bf16* wq_bf = (__bf16*)(ao + (size_t)NB * NH * NAG * 16);
  __bf16* wk_bf = wq_bf + 4096;
  __bf16* wv_bf = wk_bf + 4096;
  __bf16* wo_bf = wv_bf + 4096;
  // total ws ~= 26.9 MB

  prep_kernel<<<dim3(64), 256, 0, stream>>>(Wq, Wk, Wv, Wo, wq_bf, wk_bf, wv_bf, wo_bf);
  qkv_agent_kernel<<<dim3(NAG, NB), 256, 0, stream>>>(x1, x2, Wq, wk_bf, wv_bf, kvh, agent);
  stage0_kernel<<<dim3(NH, NB), 1024, 0, stream>>>(kvh, agent, ao);
  stage1_out_kernel<<<dim3(NAG, NB), 512, 0, stream>>>(x1, wq_bf, ao, wo_bf, bo, out);
}